// Round 19
// baseline (277.873 us; speedup 1.0000x reference)
//
#include <hip/hip_runtime.h>
#include <hip/hip_fp16.h>

#define DEVFN __device__ __forceinline__

constexpr int C   = 64;
constexpr int Hh  = 160, Ww = 160, HW = Hh * Ww;   // 25600
constexpr int B   = 2;
constexpr int P   = B * HW;                        // 51200
constexpr int NSET = 32;

typedef _Float16 f16;
typedef f16   f16x8 __attribute__((ext_vector_type(8)));
typedef float f32x4 __attribute__((ext_vector_type(4)));

// NOTE: __launch_bounds__ on every kernel (round 4).
// NOTE-2 (round 5): register arrays statically indexed everywhere.
// NOTE-3 (round 6): >~48 uniform floats/iter don't stream through SGPRs.
// NOTE-4 (round 7): >=4 independent FMA chains per loop body.
// NOTE-5 (round 8): LDS broadcast ~12cyc/b128 on the per-CU LDS pipe.
// NOTE-6 (round 9): enough waves; shrink per-thread state via f16.
// NOTE-7 (round 10): f16 K-packing halves LDS bytes + inst count.
// NOTE-8 (round 11): LDS-bound loops scale with px-per-weight-read.
// NOTE-9 (rounds 12/16/17): >=3 waves/SIMD; hoist A-frag packing/constant
// folding into prep kernels so grids can be wide.
// NOTE-10 (round 13, VALIDATED): MFMA A-frags in registers; 16x16x32_f16
// layouts; LN stats via lane-local sum + shfl_xor(16,32) in B-layout.
// NOTE-11 (round 14): KBA = GEMM + lane-local a-contraction + shfl_xor.
// NOTE-12 (round 14): MFMA B-frags from LDS-staged activations only.
// NOTE-13 (round 18): LDS stride bank math: q-quadrants offset by 4*stride
// dwords; make (4*stride_dw mod 32) != 0 (ATT 336->340 fixed a 4-way
// conflict on every read). Intermediates stored f16: halves traffic and
// deletes cvt VALU at every stage boundary (all paths damped ~0.01).

// K0: pre-pack kb_w/kb_b into A-fragment order, f16 (round-14).
__global__ __launch_bounds__(256) void k0_prep(
        const float* __restrict__ kbw, const float* __restrict__ kbb,
        f16* __restrict__ wp) {
    int e = blockIdx.x * 256 + threadIdx.x;    // 0..131071
    int j = e & 7, lane = (e >> 3) & 63, c = (e >> 9) & 1,
        mt = (e >> 10) & 7, g = e >> 13;
    int m = lane & 15, q = lane >> 4;
    int row = mt * 16 + m, s = row >> 2, o = row & 3;
    int k = c * 32 + q * 8 + j;
    float v = 0.f;
    if (k < 36)       v = kbw[(size_t)s * 2304 + g * 144 + o * 36 + k];
    else if (k == 36) v = kbb[s * 64 + g * 4 + o];
    wp[e] = (f16)v;
}

// K0c: pack A-frags for k15 (c11a) and k89 (conv3*beta, w4*lnw, w5*gamma).
__global__ __launch_bounds__(256) void k0c_pack(
        const float* __restrict__ c11aw, const float* __restrict__ conv3w,
        const float* __restrict__ beta, const float* __restrict__ w4,
        const float* __restrict__ lnw, const float* __restrict__ w5,
        const float* __restrict__ gamma, f16* __restrict__ wk) {
    int e = blockIdx.x * 256 + threadIdx.x;    // 0..20479
    if (e >= 20480) return;
    int j = e & 7, lane = (e >> 3) & 63, seg = e >> 9;
    int m = lane & 15, q = lane >> 4;
    float v;
    if (seg < 8) {
        int mt = seg >> 1, c = seg & 1, k = c * 32 + q * 8 + j;
        v = c11aw[(mt * 16 + m) * 64 + k];
    } else if (seg < 16) {
        int s3 = seg - 8, mt = s3 >> 1, c = s3 & 1, k = c * 32 + q * 8 + j;
        int co = mt * 16 + m;
        v = conv3w[co * 64 + k] * beta[co];
    } else if (seg < 32) {
        int s3 = seg - 16, mt = s3 >> 1, c = s3 & 1, k = c * 32 + q * 8 + j;
        v = w4[(mt * 16 + m) * 64 + k] * lnw[k];
    } else {
        int s3 = seg - 32, mt = s3 >> 1, c = s3 & 1, k = c * 32 + q * 8 + j;
        int co = mt * 16 + m;
        v = w5[co * 64 + k] * gamma[co];
    }
    wk[e] = (f16)v;
}

// K0d: fold bias constants for k89.
__global__ __launch_bounds__(256) void k0d_const(
        const float* __restrict__ conv3b, const float* __restrict__ beta,
        const float* __restrict__ w4, const float* __restrict__ lnb,
        const float* __restrict__ b4, const float* __restrict__ b5,
        const float* __restrict__ gamma, float* __restrict__ cbuf) {
    int tid = threadIdx.x;
    if (tid < 64) {
        cbuf[tid] = conv3b[tid] * beta[tid];
    } else if (tid < 192) {
        int j = tid - 64;
        float a = 0.f;
#pragma unroll 1
        for (int ci = 0; ci < 64; ci++)
            a = fmaf(w4[j * 64 + ci], lnb[ci], a);
        cbuf[tid] = a + b4[j];
    } else {
        int co = tid - 192;
        cbuf[tid] = b5[co] * gamma[co];
    }
}

// K15: fused LN1 + u1 via MFMA; f16 outputs; grid 3200.
__global__ __launch_bounds__(64) void k15_ln1u1(
        const float* __restrict__ inp, const float* __restrict__ lnw,
        const float* __restrict__ lnb, const f16* __restrict__ wk,
        const float* __restrict__ c11ab, f16* __restrict__ x1,
        f16* __restrict__ u1) {
    int tid = threadIdx.x;             // 0..63
    int m = tid & 15, q = tid >> 4;

    f16x8 A[4][2];
#pragma unroll
    for (int mt = 0; mt < 4; mt++)
#pragma unroll
        for (int c = 0; c < 2; c++)
            A[mt][c] = *(const f16x8*)(wk + ((mt * 2 + c) * 64 + tid) * 8);

    float lnwv[16], lnbv[16];
#pragma unroll
    for (int c = 0; c < 2; c++)
#pragma unroll
        for (int j = 0; j < 8; j++) {
            int k = c * 32 + q * 8 + j;
            lnwv[c * 8 + j] = lnw[k];
            lnbv[c * 8 + j] = lnb[k];
        }
    float bco[16];
#pragma unroll
    for (int mt = 0; mt < 4; mt++)
#pragma unroll
        for (int r = 0; r < 4; r++)
            bco[mt * 4 + r] = c11ab[mt * 16 + q * 4 + r];

    const f32x4 zero = {0.f, 0.f, 0.f, 0.f};

    int tile = blockIdx.x;
    {
        int px0 = tile * 16;
        int b = px0 / HW;
        int hw0 = px0 - b * HW;
        const float* ib = inp + (size_t)b * C * HW + hw0 + m;

        float vin[16];
#pragma unroll
        for (int c = 0; c < 2; c++)
#pragma unroll
            for (int j = 0; j < 8; j++)
                vin[c * 8 + j] = ib[(size_t)(c * 32 + q * 8 + j) * HW];

        float s = 0.f, s2 = 0.f;
#pragma unroll
        for (int i = 0; i < 16; i++) { s += vin[i]; s2 += vin[i] * vin[i]; }
        s  += __shfl_xor(s, 16);  s  += __shfl_xor(s, 32);
        s2 += __shfl_xor(s2, 16); s2 += __shfl_xor(s2, 32);
        float mu  = s * (1.f / 64.f);
        float var = fmaxf(s2 * (1.f / 64.f) - mu * mu, 0.f);
        float r   = rsqrtf(var + 1e-6f);

        f16* xo = x1 + (size_t)b * C * HW + hw0 + m;
        f16x8 BX[2];
#pragma unroll
        for (int c = 0; c < 2; c++)
#pragma unroll
            for (int j = 0; j < 8; j++) {
                float v = (vin[c * 8 + j] - mu) * r * lnwv[c * 8 + j] + lnbv[c * 8 + j];
                BX[c][j] = (f16)v;
                xo[(size_t)(c * 32 + q * 8 + j) * HW] = (f16)v;
            }

        f32x4 acc[4];
#pragma unroll
        for (int mt = 0; mt < 4; mt++) {
            acc[mt] = __builtin_amdgcn_mfma_f32_16x16x32_f16(A[mt][0], BX[0], zero, 0, 0, 0);
            acc[mt] = __builtin_amdgcn_mfma_f32_16x16x32_f16(A[mt][1], BX[1], acc[mt], 0, 0, 0);
        }
        f16* uo = u1 + (size_t)b * C * HW + hw0 + m;
#pragma unroll
        for (int mt = 0; mt < 4; mt++)
#pragma unroll
            for (int r2 = 0; r2 < 4; r2++) {
                int co = mt * 16 + q * 4 + r2;
                uo[(size_t)co * HW] = (f16)(acc[mt][r2] + bco[mt * 4 + r2]);
            }
    }
}

// K2: spatial mean of x1 per (b,c); 512 blocks, atomic partials.
__global__ __launch_bounds__(256) void k2_mean(
        const f16* __restrict__ x1, float* __restrict__ meanb) {
    int blk = blockIdx.x;                        // 0..511
    int bc = blk >> 2, quarter = blk & 3;
    const f16* src = x1 + (size_t)bc * HW + quarter * (HW / 4);
    float s = 0.f;
    for (int i = threadIdx.x; i < HW / 4; i += 256) s += (float)src[i];
#pragma unroll
    for (int o = 32; o > 0; o >>= 1) s += __shfl_down(s, o);
    __shared__ float red[4];
    if ((threadIdx.x & 63) == 0) red[threadIdx.x >> 6] = s;
    __syncthreads();
    if (threadIdx.x == 0)
        atomicAdd(&meanb[bc],
                  (red[0] + red[1] + red[2] + red[3]) * (1.f / HW));
}

// K3: sca = sca_w @ mean + sca_b   [B,64]
__global__ __launch_bounds__(256) void k3_sca(
        const float* __restrict__ scaw, const float* __restrict__ scab_,
        const float* __restrict__ meanb, float* __restrict__ sca) {
    int t = threadIdx.x;
    if (t >= 128) return;
    int b = t >> 6, c = t & 63;
    float acc = scab_[c];
#pragma unroll
    for (int k = 0; k < 64; k++)
        acc = fmaf(scaw[c * 64 + k], meanb[b * 64 + k], acc);
    sca[t] = acc;
}

// K4-v2: att with o-dim split across lane quarters (round 17); f16 I/O.
__global__ __launch_bounds__(128) void k4_att2(
        const f16* __restrict__ x1, const float* __restrict__ c2aw,
        const float* __restrict__ c2ab, const float* __restrict__ c2bw,
        const float* __restrict__ c2bb, const float* __restrict__ attg,
        f16* __restrict__ att) {
    __shared__ float Wf[1184];
    int tid = threadIdx.x;
    for (int e = tid; e < 1184; e += 128) {
        float v;
        if (e < 576)       v = c2aw[e];
        else if (e < 608)  v = c2ab[e - 576];
        else if (e < 1120) v = c2bw[e - 608];
        else if (e < 1152) v = c2bb[e - 1120];
        else               v = attg[e - 1152];
        Wf[e] = v;
    }
    __syncthreads();

    int wv = tid >> 6, lane = tid & 63;
    int i = lane & 15, q = lane >> 4;
    int p = blockIdx.x * 32 + wv * 16 + i;    // 32 px per block
    int b = p / HW, hw = p % HW, h = hw / Ww, w = hw % Ww;
    const f16* xb = x1 + (size_t)b * C * HW;
    bool interior = (h >= 1 && h < Hh - 1 && w >= 1 && w < Ww - 1);

    float t[8];
#pragma unroll
    for (int j = 0; j < 8; j++) {
        int o = q * 8 + j;
        float acc = Wf[576 + o];
#pragma unroll
        for (int k = 0; k < 2; k++) {
            const f16* xc = xb + (size_t)(2 * o + k) * HW;
            const float* wr = &Wf[(o * 2 + k) * 9];
            if (interior) {
#pragma unroll
                for (int kh = 0; kh < 3; kh++)
#pragma unroll
                    for (int kw = 0; kw < 3; kw++)
                        acc = fmaf(wr[kh * 3 + kw],
                                   (float)xc[(h + kh - 1) * Ww + (w + kw - 1)], acc);
            } else {
#pragma unroll
                for (int kh = 0; kh < 3; kh++) {
                    int y = h + kh - 1;
#pragma unroll
                    for (int kw = 0; kw < 3; kw++) {
                        int x = w + kw - 1;
                        if ((unsigned)y < (unsigned)Hh && (unsigned)x < (unsigned)Ww)
                            acc = fmaf(wr[kh * 3 + kw], (float)xc[y * Ww + x], acc);
                    }
                }
            }
        }
        t[j] = acc;
    }

    float g_[8], g2_[8];
#pragma unroll
    for (int j = 0; j < 8; j++) g_[j] = t[j] * __shfl_xor(t[j], 32);
#pragma unroll
    for (int j = 0; j < 8; j++) g2_[j] = __shfl_xor(g_[j], 16);
    float glo[8], ghi[8];
    bool hiq = (q & 1);
#pragma unroll
    for (int j = 0; j < 8; j++) {
        glo[j] = hiq ? g2_[j] : g_[j];
        ghi[j] = hiq ? g_[j] : g2_[j];
    }

    f16* ad = att + (size_t)b * NSET * HW + hw;
#pragma unroll
    for (int j = 0; j < 8; j++) {
        int s = q * 8 + j;
        float acc = Wf[1120 + s];
        const float* wr = &Wf[608 + s * 16];
#pragma unroll
        for (int c = 0; c < 8; c++) acc = fmaf(wr[c], glo[c], acc);
#pragma unroll
        for (int c = 0; c < 8; c++) acc = fmaf(wr[8 + c], ghi[c], acc);
        ad[(size_t)s * HW] = (f16)(acc * Wf[1152 + s]);
    }
}

// K6: uf = 5x5 grouped conv (groups=16) of u1, pad=2; f16 I/O.
__global__ __launch_bounds__(128) void k6_uf(
        const f16* __restrict__ u1, const float* __restrict__ w,
        const float* __restrict__ bias, f16* __restrict__ uf) {
    __shared__ float wsm[404];
    int blk = blockIdx.x;              // 0..1599
    int g   = blk / 100;               // 0..15 uniform
    int ublk = blk % 100;
    int tid = threadIdx.x;
    for (int e = tid; e < 400; e += 128) {
        int o = e / 100, rest = e - o * 100, cl = rest / 25, tp = rest - cl * 25;
        wsm[e] = w[(((g * 4 + o) * 4) + cl) * 25 + tp];
    }
    if (tid < 4) wsm[400 + tid] = bias[g * 4 + tid];
    __syncthreads();

    int unit = ublk * 128 + tid;
    int b  = unit / (HW / 4);
    int rr = unit - b * (HW / 4);
    int r4 = rr / Ww, w_ = rr - r4 * Ww;
    int hA = r4 * 4;
    int hw0 = hA * Ww + w_;
    bool interior = (w_ >= 2 && w_ < Ww - 2 && r4 >= 1 && r4 <= 38);

    float acc[16];
#pragma unroll
    for (int i = 0; i < 16; i++) acc[i] = wsm[400 + (i & 3)];

#pragma unroll 1
    for (int cl = 0; cl < 4; cl++) {
        const f16* src = u1 + (size_t)(b * C + g * 4 + cl) * HW;
        float tv[40];
        if (interior) {
#pragma unroll
            for (int rrow = 0; rrow < 8; rrow++)
#pragma unroll
                for (int kw = 0; kw < 5; kw++)
                    tv[rrow * 5 + kw] = (float)src[(hA - 2 + rrow) * Ww + (w_ - 2 + kw)];
        } else {
#pragma unroll
            for (int rrow = 0; rrow < 8; rrow++) {
                int y = hA - 2 + rrow;
#pragma unroll
                for (int kw = 0; kw < 5; kw++) {
                    int x = w_ - 2 + kw;
                    tv[rrow * 5 + kw] =
                        ((unsigned)y < (unsigned)Hh && (unsigned)x < (unsigned)Ww)
                            ? (float)src[y * Ww + x] : 0.f;
                }
            }
        }
#pragma unroll
        for (int o = 0; o < 4; o++) {
            const float* wr = &wsm[(o * 4 + cl) * 25];
#pragma unroll
            for (int kh = 0; kh < 5; kh++)
#pragma unroll
                for (int kw = 0; kw < 5; kw++) {
                    float wv = wr[kh * 5 + kw];
                    acc[0 * 4 + o] = fmaf(wv, tv[(kh + 0) * 5 + kw], acc[0 * 4 + o]);
                    acc[1 * 4 + o] = fmaf(wv, tv[(kh + 1) * 5 + kw], acc[1 * 4 + o]);
                    acc[2 * 4 + o] = fmaf(wv, tv[(kh + 2) * 5 + kw], acc[2 * 4 + o]);
                    acc[3 * 4 + o] = fmaf(wv, tv[(kh + 3) * 5 + kw], acc[3 * 4 + o]);
                }
        }
    }
    f16* dst = uf + (size_t)(b * C + g * 4) * HW;
#pragma unroll
    for (int o = 0; o < 4; o++)
#pragma unroll
        for (int px = 0; px < 4; px++)
            dst[o * HW + hw0 + px * Ww] = (f16)acc[px * 4 + o];
}

// K7-MFMA-v3: KBA GEMM + LDS staging, f16 global I/O, u32-pair staging,
// ATT stride 340 (NOTE-13: conflict-free across q), UF stride 164.
constexpr int ATTS = 340;                // f16 units; 170 u32
__global__ __launch_bounds__(256) void k7_mfma2(
        const f16* __restrict__ att, const f16* __restrict__ uf,
        const f16* __restrict__ wp, const float* __restrict__ ga1,
        const float* __restrict__ sca, f16* __restrict__ xmid) {
    __shared__ unsigned UFa[4 * 4 * 82];   // [cl][r][82 u32] = f16 stride 164
    __shared__ unsigned ATTa[32 * 170];    // [s][170 u32]    = f16 stride 340
    f16* UF  = (f16*)UFa;
    f16* ATT = (f16*)ATTa;
    int bi  = blockIdx.x;                // 0..2559
    int g   = bi / 160;                  // uniform
    int rp  = bi % 160;
    int b   = rp / 80;
    int h0  = (rp % 80) * 2;
    int hw0 = h0 * Ww;
    int tid = threadIdx.x;
    int wv  = tid >> 6, lane = tid & 63;
    int m   = lane & 15, q = lane >> 4;

    // stage UF halo rows h0-1..h0+2 as u32 pairs (data at f16 col 2+x)
    {
        const unsigned* uf32 = (const unsigned*)uf;
        for (int e = tid; e < 1280; e += 256) {
            int cl = e / 320, r = (e / 80) & 3, xw = e % 80;
            int y = h0 - 1 + r;
            unsigned v = 0u;
            if ((unsigned)y < (unsigned)Hh)
                v = uf32[((size_t)(b * C + g * 4 + cl) * HW >> 1) + y * 80 + xw];
            UFa[cl * 328 + r * 82 + 1 + xw] = v;
        }
        if (tid < 32) {
            int cl = tid >> 3, r = (tid >> 1) & 3, side = tid & 1;
            UFa[cl * 328 + r * 82 + side * 81] = 0u;
        }
    }
    // stage ATT as u32 pairs
    {
        const unsigned* ab32 =
            (const unsigned*)(att + (size_t)b * NSET * HW + hw0);
        for (int e = tid; e < 5120; e += 256) {
            int s = e / 160, pw = e % 160;
            ATTa[s * 170 + pw] = ab32[(size_t)s * (HW >> 1) + pw];
        }
    }

    f16x8 A[8][2];
    const f16* wpg = wp + (size_t)g * 8 * 2 * 64 * 8;
#pragma unroll
    for (int mt = 0; mt < 8; mt++)
#pragma unroll
        for (int c = 0; c < 2; c++)
            A[mt][c] = *(const f16x8*)(wpg + ((mt * 2 + c) * 64 + lane) * 8);

    int off0[8];
#pragma unroll
    for (int j = 0; j < 8; j++) {
        int i = q * 8 + j;
        int cl = i / 9, rr = i - cl * 9, kh = rr / 3, kw = rr - kh * 3;
        off0[j] = cl * 656 + kh * 164 + kw;
    }
    int off1[4];
#pragma unroll
    for (int j = 0; j < 4; j++) {
        int i = 32 + j;                  // cl=3
        int rr = i - 27, kh = rr / 3, kw = rr - kh * 3;
        off1[j] = 3 * 656 + kh * 164 + kw;
    }

    float gav[4], scb[4];
#pragma unroll
    for (int r = 0; r < 4; r++) {
        gav[r] = ga1[g * 4 + r];
        scb[r] = sca[b * 64 + g * 4 + r];
    }

    __syncthreads();
    const f32x4 zero = {0.f, 0.f, 0.f, 0.f};

#pragma unroll 1
    for (int t = wv; t < 20; t += 4) {       // 5 tiles per wave
        int tr = t / 10, col0 = (t - tr * 10) * 16;
        int tbase = tr * 164 + col0 + m + 1;
        int pxb   = tr * 160 + col0 + m;

        f16x8 B0, B1;
#pragma unroll
        for (int j = 0; j < 8; j++) B0[j] = UF[off0[j] + tbase];
        if (q == 0) {
#pragma unroll
            for (int j = 0; j < 4; j++) B1[j] = UF[off1[j] + tbase];
            B1[4] = (f16)1.f;
            B1[5] = (f16)0.f; B1[6] = (f16)0.f; B1[7] = (f16)0.f;
        } else {
#pragma unroll
            for (int j = 0; j < 8; j++) B1[j] = (f16)0.f;
        }

        f32x4 acc[8];
#pragma unroll
        for (int mt = 0; mt < 8; mt++) {
            acc[mt] = __builtin_amdgcn_mfma_f32_16x16x32_f16(A[mt][0], B0, zero, 0, 0, 0);
            acc[mt] = __builtin_amdgcn_mfma_f32_16x16x32_f16(A[mt][1], B1, acc[mt], 0, 0, 0);
        }

        float o4[4] = {0.f, 0.f, 0.f, 0.f};
#pragma unroll
        for (int mt = 0; mt < 8; mt++) {
            float av = (float)ATT[(mt * 4 + q) * ATTS + pxb];
#pragma unroll
            for (int r = 0; r < 4; r++) o4[r] = fmaf(av, acc[mt][r], o4[r]);
        }
#pragma unroll
        for (int r = 0; r < 4; r++) {
            o4[r] += __shfl_xor(o4[r], 16);
            o4[r] += __shfl_xor(o4[r], 32);
        }
        if (q == 0) {
            int hw = hw0 + pxb;
#pragma unroll
            for (int r = 0; r < 4; r++) {
                int co = g * 4 + r;
                float cf = (float)uf[(size_t)(b * C + co) * HW + hw];
                xmid[(size_t)(b * C + co) * HW + hw] =
                    (f16)((o4[r] * gav[r] + cf) * scb[r]);
            }
        }
    }
}

// K89-MFMA-v3: conv3+residual+LN2+FFN; xmid read as f16 B-frags directly.
__global__ __launch_bounds__(64) void k89_mfma(
        const f16* __restrict__ xmid, const float* __restrict__ inp,
        const f16* __restrict__ wk, const float* __restrict__ cbuf,
        float* __restrict__ out) {
    __shared__ float CONST[256];
    __shared__ f16 TBUF[16 * 72];  // [n][k], stride 72

    int tid = threadIdx.x;         // 0..63
    int m = tid & 15, q = tid >> 4;

    CONST[tid] = cbuf[tid];
    CONST[64 + tid] = cbuf[64 + tid];
    CONST[128 + tid] = cbuf[128 + tid];
    CONST[192 + tid] = cbuf[192 + tid];

    f16x8 A3[4][2], A4[8][2], A5[4][2];
#pragma unroll
    for (int mt = 0; mt < 4; mt++)
#pragma unroll
        for (int c = 0; c < 2; c++) {
            A3[mt][c] = *(const f16x8*)(wk + ((8 + mt * 2 + c) * 64 + tid) * 8);
            A5[mt][c] = *(const f16x8*)(wk + ((32 + mt * 2 + c) * 64 + tid) * 8);
        }
#pragma unroll
    for (int mt = 0; mt < 8; mt++)
#pragma unroll
        for (int c = 0; c < 2; c++)
            A4[mt][c] = *(const f16x8*)(wk + ((16 + mt * 2 + c) * 64 + tid) * 8);
    __syncthreads();

    float c3i[16], b5g[16];
#pragma unroll
    for (int mt = 0; mt < 4; mt++)
#pragma unroll
        for (int r = 0; r < 4; r++) {
            c3i[mt * 4 + r] = CONST[mt * 16 + q * 4 + r];
            b5g[mt * 4 + r] = CONST[192 + mt * 16 + q * 4 + r];
        }

    const f32x4 zero = {0.f, 0.f, 0.f, 0.f};

    int tile = blockIdx.x;
    {
        int px0 = tile * 16;
        int b = px0 / HW;
        int hw0 = px0 - b * HW;
        const f16* xb = xmid + (size_t)b * C * HW + hw0 + m;
        const float* ib = inp + (size_t)b * C * HW + hw0 + m;
        float* ob = out + (size_t)b * C * HW + hw0 + m;

        f16x8 BX[2];
#pragma unroll
        for (int c = 0; c < 2; c++)
#pragma unroll
            for (int j = 0; j < 8; j++)
                BX[c][j] = xb[(size_t)(c * 32 + q * 8 + j) * HW];

        f32x4 accY[4];
#pragma unroll
        for (int mt = 0; mt < 4; mt++) {
            accY[mt] = __builtin_amdgcn_mfma_f32_16x16x32_f16(A3[mt][0], BX[0], zero, 0, 0, 0);
            accY[mt] = __builtin_amdgcn_mfma_f32_16x16x32_f16(A3[mt][1], BX[1], accY[mt], 0, 0, 0);
        }
        float y[16];
#pragma unroll
        for (int mt = 0; mt < 4; mt++)
#pragma unroll
            for (int r = 0; r < 4; r++) {
                int co = mt * 16 + q * 4 + r;
                y[mt * 4 + r] = ib[(size_t)co * HW] + accY[mt][r] + c3i[mt * 4 + r];
            }

        float s = 0.f, s2 = 0.f;
#pragma unroll
        for (int i = 0; i < 16; i++) { s += y[i]; s2 += y[i] * y[i]; }
        s  += __shfl_xor(s, 16);  s  += __shfl_xor(s, 32);
        s2 += __shfl_xor(s2, 16); s2 += __shfl_xor(s2, 32);
        float mu  = s * (1.f / 64.f);
        float var = fmaxf(s2 * (1.f / 64.f) - mu * mu, 0.f);
        float rr  = rsqrtf(var + 1e-6f);

#pragma unroll
        for (int mt = 0; mt < 4; mt++)
#pragma unroll
            for (int r = 0; r < 4; r++)
                TBUF[m * 72 + mt * 16 + q * 4 + r] = (f16)(y[mt * 4 + r] - mu);
        __syncthreads();
        f16x8 BV[2];
#pragma unroll
        for (int c = 0; c < 2; c++)
#pragma unroll
            for (int j = 0; j < 8; j++)
                BV[c][j] = TBUF[m * 72 + c * 32 + q * 8 + j];

        f32x4 accT[8];
#pragma unroll
        for (int mt = 0; mt < 8; mt++) {
            accT[mt] = __builtin_amdgcn_mfma_f32_16x16x32_f16(A4[mt][0], BV[0], zero, 0, 0, 0);
            accT[mt] = __builtin_amdgcn_mfma_f32_16x16x32_f16(A4[mt][1], BV[1], accT[mt], 0, 0, 0);
        }
        __syncthreads();

#pragma unroll
        for (int mt = 0; mt < 4; mt++)
#pragma unroll
            for (int r = 0; r < 4; r++) {
                int j = mt * 16 + q * 4 + r;
                float t1 = rr * accT[mt][r] + CONST[64 + j];
                float t2 = rr * accT[mt + 4][r] + CONST[128 + j];
                TBUF[m * 72 + j] = (f16)(t1 * t2);
            }
        __syncthreads();
        f16x8 BG[2];
#pragma unroll
        for (int c = 0; c < 2; c++)
#pragma unroll
            for (int j = 0; j < 8; j++)
                BG[c][j] = TBUF[m * 72 + c * 32 + q * 8 + j];

        f32x4 accO[4];
#pragma unroll
        for (int mt = 0; mt < 4; mt++) {
            accO[mt] = __builtin_amdgcn_mfma_f32_16x16x32_f16(A5[mt][0], BG[0], zero, 0, 0, 0);
            accO[mt] = __builtin_amdgcn_mfma_f32_16x16x32_f16(A5[mt][1], BG[1], accO[mt], 0, 0, 0);
        }
#pragma unroll
        for (int mt = 0; mt < 4; mt++)
#pragma unroll
            for (int r = 0; r < 4; r++) {
                int co = mt * 16 + q * 4 + r;
                ob[(size_t)co * HW] = y[mt * 4 + r] + accO[mt][r] + b5g[mt * 4 + r];
            }
    }
}

extern "C" void kernel_launch(void* const* d_in, const int* in_sizes, int n_in,
                              void* d_out, int out_size, void* d_ws, size_t ws_size,
                              hipStream_t stream) {
    (void)in_sizes; (void)n_in; (void)out_size; (void)ws_size;

    const float* inp     = (const float*)d_in[0];
    const float* ln1_w   = (const float*)d_in[1];
    const float* ln1_b   = (const float*)d_in[2];
    const float* ln2_w   = (const float*)d_in[3];
    const float* ln2_b   = (const float*)d_in[4];
    const float* sca_w   = (const float*)d_in[5];
    const float* sca_b   = (const float*)d_in[6];
    const float* c11a_w  = (const float*)d_in[7];
    const float* c11a_b  = (const float*)d_in[8];
    const float* c11b_w  = (const float*)d_in[9];
    const float* c11b_b  = (const float*)d_in[10];
    const float* c2a_w   = (const float*)d_in[11];
    const float* c2a_b   = (const float*)d_in[12];
    const float* c2b_w   = (const float*)d_in[13];
    const float* c2b_b   = (const float*)d_in[14];
    const float* conv3_w = (const float*)d_in[15];
    const float* conv3_b = (const float*)d_in[16];
    const float* conv4_w = (const float*)d_in[17];
    const float* conv4_b = (const float*)d_in[18];
    const float* conv5_w = (const float*)d_in[19];
    const float* conv5_b = (const float*)d_in[20];
    const float* kb_w    = (const float*)d_in[21];
    const float* kb_b    = (const float*)d_in[22];
    const float* ga1     = (const float*)d_in[23];
    const float* attg    = (const float*)d_in[24];
    const float* beta    = (const float*)d_in[25];
    const float* gamma   = (const float*)d_in[26];

    // ---- ws arena ----
    char* ws = (char*)d_ws;
    size_t off = 0;
    auto alloc = [&](size_t bytes) {
        void* r = ws + off;
        off += (bytes + 255) & ~(size_t)255;
        return r;
    };
    f16*   wpk   = (f16*)alloc(131072 * 2);             // 256 KB packed KBA W
    f16*   wk2   = (f16*)alloc(20480 * 2);              // 40 KB packed A-frags
    float* cbuf  = (float*)alloc(256 * 4);
    float* meanb = (float*)alloc(128 * 4);
    float* scab  = (float*)alloc(128 * 4);
    f16*   x1    = (f16*)alloc((size_t)P * 64 * 2);     // 6.55 MB
    f16*   attb  = (f16*)alloc((size_t)P * 32 * 2);     // 3.28 MB
    f16*   u1    = (f16*)alloc((size_t)P * 64 * 2);     // 6.55 MB
    f16*   ufb   = x1;   // x1 dead after K4
    f16*   xmid  = u1;   // u1 dead after K6

    hipMemsetAsync(meanb, 0, 128 * 4, stream);

    k0_prep  <<<512, 256, 0, stream>>>(kb_w, kb_b, wpk);
    k0c_pack <<<80, 256, 0, stream>>>(c11a_w, conv3_w, beta, conv4_w, ln2_w,
                                      conv5_w, gamma, wk2);
    k0d_const<<<1, 256, 0, stream>>>(conv3_b, beta, conv4_w, ln2_b, conv4_b,
                                     conv5_b, gamma, cbuf);
    k15_ln1u1<<<3200, 64, 0, stream>>>(inp, ln1_w, ln1_b, wk2, c11a_b,
                                       x1, u1);
    k2_mean  <<<512, 256, 0, stream>>>(x1, meanb);
    k3_sca   <<<1, 128, 0, stream>>>(sca_w, sca_b, meanb, scab);
    k4_att2  <<<P / 32, 128, 0, stream>>>(x1, c2a_w, c2a_b, c2b_w, c2b_b,
                                          attg, attb);
    k6_uf    <<<1600, 128, 0, stream>>>(u1, c11b_w, c11b_b, ufb);
    k7_mfma2 <<<2560, 256, 0, stream>>>(attb, ufb, wpk, ga1, scab, xmid);
    k89_mfma <<<3200, 64, 0, stream>>>(xmid, inp, wk2, cbuf, (float*)d_out);
}

// Round 20
// 257.539 us; speedup vs baseline: 1.0790x; 1.0790x over previous
//
#include <hip/hip_runtime.h>
#include <hip/hip_fp16.h>

#define DEVFN __device__ __forceinline__

constexpr int C   = 64;
constexpr int Hh  = 160, Ww = 160, HW = Hh * Ww;   // 25600
constexpr int B   = 2;
constexpr int P   = B * HW;                        // 51200
constexpr int NSET = 32;

typedef _Float16 f16;
typedef f16   f16x8 __attribute__((ext_vector_type(8)));
typedef float f32x4 __attribute__((ext_vector_type(4)));

// NOTE: __launch_bounds__ on every kernel (round 4).
// NOTE-2 (round 5): register arrays statically indexed everywhere.
// NOTE-3 (round 6): >~48 uniform floats/iter don't stream through SGPRs.
// NOTE-4 (round 7): >=4 independent FMA chains per loop body.
// NOTE-5 (round 8): LDS broadcast ~12cyc/b128 on the per-CU LDS pipe.
// NOTE-6 (round 9): enough waves; shrink per-thread state via f16.
// NOTE-7 (round 10): f16 K-packing halves LDS bytes + inst count.
// NOTE-8 (round 11): LDS-bound loops scale with px-per-weight-read.
// NOTE-9 (rounds 12/16/17): >=3 waves/SIMD; hoist packing to prep kernels.
// NOTE-10 (round 13): MFMA A-frags in registers; 16x16x32_f16 layouts; LN
// via shfl_xor(16,32) in B-layout.
// NOTE-11 (round 14): KBA = GEMM + lane-local a-contraction + shfl_xor.
// NOTE-12 (rounds 14/19): activations feeding scattered/tap reads must be
// LDS-staged via coalesced u32 loads; per-thread scalar f16 global tap
// loads are latency-death (k6 r19: VALU 15%).
// NOTE-13 (round 18): LDS stride bank math: make (4*stride_dw mod 32)!=0.
// f16 intermediates halve traffic; all paths damped ~0.01.

// K0: pre-pack kb_w/kb_b into A-fragment order, f16 (round-14).
__global__ __launch_bounds__(256) void k0_prep(
        const float* __restrict__ kbw, const float* __restrict__ kbb,
        f16* __restrict__ wp) {
    int e = blockIdx.x * 256 + threadIdx.x;    // 0..131071
    int j = e & 7, lane = (e >> 3) & 63, c = (e >> 9) & 1,
        mt = (e >> 10) & 7, g = e >> 13;
    int m = lane & 15, q = lane >> 4;
    int row = mt * 16 + m, s = row >> 2, o = row & 3;
    int k = c * 32 + q * 8 + j;
    float v = 0.f;
    if (k < 36)       v = kbw[(size_t)s * 2304 + g * 144 + o * 36 + k];
    else if (k == 36) v = kbb[s * 64 + g * 4 + o];
    wp[e] = (f16)v;
}

// K0c: pack A-frags for k15 (c11a) and k89 (conv3*beta, w4*lnw, w5*gamma).
__global__ __launch_bounds__(256) void k0c_pack(
        const float* __restrict__ c11aw, const float* __restrict__ conv3w,
        const float* __restrict__ beta, const float* __restrict__ w4,
        const float* __restrict__ lnw, const float* __restrict__ w5,
        const float* __restrict__ gamma, f16* __restrict__ wk) {
    int e = blockIdx.x * 256 + threadIdx.x;    // 0..20479
    if (e >= 20480) return;
    int j = e & 7, lane = (e >> 3) & 63, seg = e >> 9;
    int m = lane & 15, q = lane >> 4;
    float v;
    if (seg < 8) {
        int mt = seg >> 1, c = seg & 1, k = c * 32 + q * 8 + j;
        v = c11aw[(mt * 16 + m) * 64 + k];
    } else if (seg < 16) {
        int s3 = seg - 8, mt = s3 >> 1, c = s3 & 1, k = c * 32 + q * 8 + j;
        int co = mt * 16 + m;
        v = conv3w[co * 64 + k] * beta[co];
    } else if (seg < 32) {
        int s3 = seg - 16, mt = s3 >> 1, c = s3 & 1, k = c * 32 + q * 8 + j;
        v = w4[(mt * 16 + m) * 64 + k] * lnw[k];
    } else {
        int s3 = seg - 32, mt = s3 >> 1, c = s3 & 1, k = c * 32 + q * 8 + j;
        int co = mt * 16 + m;
        v = w5[co * 64 + k] * gamma[co];
    }
    wk[e] = (f16)v;
}

// K0d: fold bias constants for k89.
__global__ __launch_bounds__(256) void k0d_const(
        const float* __restrict__ conv3b, const float* __restrict__ beta,
        const float* __restrict__ w4, const float* __restrict__ lnb,
        const float* __restrict__ b4, const float* __restrict__ b5,
        const float* __restrict__ gamma, float* __restrict__ cbuf) {
    int tid = threadIdx.x;
    if (tid < 64) {
        cbuf[tid] = conv3b[tid] * beta[tid];
    } else if (tid < 192) {
        int j = tid - 64;
        float a = 0.f;
#pragma unroll 1
        for (int ci = 0; ci < 64; ci++)
            a = fmaf(w4[j * 64 + ci], lnb[ci], a);
        cbuf[tid] = a + b4[j];
    } else {
        int co = tid - 192;
        cbuf[tid] = b5[co] * gamma[co];
    }
}

// K15: fused LN1 + u1 via MFMA; f16 outputs; grid 3200.
__global__ __launch_bounds__(64) void k15_ln1u1(
        const float* __restrict__ inp, const float* __restrict__ lnw,
        const float* __restrict__ lnb, const f16* __restrict__ wk,
        const float* __restrict__ c11ab, f16* __restrict__ x1,
        f16* __restrict__ u1) {
    int tid = threadIdx.x;             // 0..63
    int m = tid & 15, q = tid >> 4;

    f16x8 A[4][2];
#pragma unroll
    for (int mt = 0; mt < 4; mt++)
#pragma unroll
        for (int c = 0; c < 2; c++)
            A[mt][c] = *(const f16x8*)(wk + ((mt * 2 + c) * 64 + tid) * 8);

    float lnwv[16], lnbv[16];
#pragma unroll
    for (int c = 0; c < 2; c++)
#pragma unroll
        for (int j = 0; j < 8; j++) {
            int k = c * 32 + q * 8 + j;
            lnwv[c * 8 + j] = lnw[k];
            lnbv[c * 8 + j] = lnb[k];
        }
    float bco[16];
#pragma unroll
    for (int mt = 0; mt < 4; mt++)
#pragma unroll
        for (int r = 0; r < 4; r++)
            bco[mt * 4 + r] = c11ab[mt * 16 + q * 4 + r];

    const f32x4 zero = {0.f, 0.f, 0.f, 0.f};

    int tile = blockIdx.x;
    {
        int px0 = tile * 16;
        int b = px0 / HW;
        int hw0 = px0 - b * HW;
        const float* ib = inp + (size_t)b * C * HW + hw0 + m;

        float vin[16];
#pragma unroll
        for (int c = 0; c < 2; c++)
#pragma unroll
            for (int j = 0; j < 8; j++)
                vin[c * 8 + j] = ib[(size_t)(c * 32 + q * 8 + j) * HW];

        float s = 0.f, s2 = 0.f;
#pragma unroll
        for (int i = 0; i < 16; i++) { s += vin[i]; s2 += vin[i] * vin[i]; }
        s  += __shfl_xor(s, 16);  s  += __shfl_xor(s, 32);
        s2 += __shfl_xor(s2, 16); s2 += __shfl_xor(s2, 32);
        float mu  = s * (1.f / 64.f);
        float var = fmaxf(s2 * (1.f / 64.f) - mu * mu, 0.f);
        float r   = rsqrtf(var + 1e-6f);

        f16* xo = x1 + (size_t)b * C * HW + hw0 + m;
        f16x8 BX[2];
#pragma unroll
        for (int c = 0; c < 2; c++)
#pragma unroll
            for (int j = 0; j < 8; j++) {
                float v = (vin[c * 8 + j] - mu) * r * lnwv[c * 8 + j] + lnbv[c * 8 + j];
                BX[c][j] = (f16)v;
                xo[(size_t)(c * 32 + q * 8 + j) * HW] = (f16)v;
            }

        f32x4 acc[4];
#pragma unroll
        for (int mt = 0; mt < 4; mt++) {
            acc[mt] = __builtin_amdgcn_mfma_f32_16x16x32_f16(A[mt][0], BX[0], zero, 0, 0, 0);
            acc[mt] = __builtin_amdgcn_mfma_f32_16x16x32_f16(A[mt][1], BX[1], acc[mt], 0, 0, 0);
        }
        f16* uo = u1 + (size_t)b * C * HW + hw0 + m;
#pragma unroll
        for (int mt = 0; mt < 4; mt++)
#pragma unroll
            for (int r2 = 0; r2 < 4; r2++) {
                int co = mt * 16 + q * 4 + r2;
                uo[(size_t)co * HW] = (f16)(acc[mt][r2] + bco[mt * 4 + r2]);
            }
    }
}

// K2: spatial mean of x1 per (b,c); 512 blocks, atomic partials.
__global__ __launch_bounds__(256) void k2_mean(
        const f16* __restrict__ x1, float* __restrict__ meanb) {
    int blk = blockIdx.x;                        // 0..511
    int bc = blk >> 2, quarter = blk & 3;
    const f16* src = x1 + (size_t)bc * HW + quarter * (HW / 4);
    float s = 0.f;
    for (int i = threadIdx.x; i < HW / 4; i += 256) s += (float)src[i];
#pragma unroll
    for (int o = 32; o > 0; o >>= 1) s += __shfl_down(s, o);
    __shared__ float red[4];
    if ((threadIdx.x & 63) == 0) red[threadIdx.x >> 6] = s;
    __syncthreads();
    if (threadIdx.x == 0)
        atomicAdd(&meanb[bc],
                  (red[0] + red[1] + red[2] + red[3]) * (1.f / HW));
}

// K3: sca = sca_w @ mean + sca_b   [B,64]
__global__ __launch_bounds__(256) void k3_sca(
        const float* __restrict__ scaw, const float* __restrict__ scab_,
        const float* __restrict__ meanb, float* __restrict__ sca) {
    int t = threadIdx.x;
    if (t >= 128) return;
    int b = t >> 6, c = t & 63;
    float acc = scab_[c];
#pragma unroll
    for (int k = 0; k < 64; k++)
        acc = fmaf(scaw[c * 64 + k], meanb[b * 64 + k], acc);
    sca[t] = acc;
}

// K4-v2: att with o-dim split across lane quarters (round 17); f16 I/O.
__global__ __launch_bounds__(128) void k4_att2(
        const f16* __restrict__ x1, const float* __restrict__ c2aw,
        const float* __restrict__ c2ab, const float* __restrict__ c2bw,
        const float* __restrict__ c2bb, const float* __restrict__ attg,
        f16* __restrict__ att) {
    __shared__ float Wf[1184];
    int tid = threadIdx.x;
    for (int e = tid; e < 1184; e += 128) {
        float v;
        if (e < 576)       v = c2aw[e];
        else if (e < 608)  v = c2ab[e - 576];
        else if (e < 1120) v = c2bw[e - 608];
        else if (e < 1152) v = c2bb[e - 1120];
        else               v = attg[e - 1152];
        Wf[e] = v;
    }
    __syncthreads();

    int wv = tid >> 6, lane = tid & 63;
    int i = lane & 15, q = lane >> 4;
    int p = blockIdx.x * 32 + wv * 16 + i;    // 32 px per block
    int b = p / HW, hw = p % HW, h = hw / Ww, w = hw % Ww;
    const f16* xb = x1 + (size_t)b * C * HW;
    bool interior = (h >= 1 && h < Hh - 1 && w >= 1 && w < Ww - 1);

    float t[8];
#pragma unroll
    for (int j = 0; j < 8; j++) {
        int o = q * 8 + j;
        float acc = Wf[576 + o];
#pragma unroll
        for (int k = 0; k < 2; k++) {
            const f16* xc = xb + (size_t)(2 * o + k) * HW;
            const float* wr = &Wf[(o * 2 + k) * 9];
            if (interior) {
#pragma unroll
                for (int kh = 0; kh < 3; kh++)
#pragma unroll
                    for (int kw = 0; kw < 3; kw++)
                        acc = fmaf(wr[kh * 3 + kw],
                                   (float)xc[(h + kh - 1) * Ww + (w + kw - 1)], acc);
            } else {
#pragma unroll
                for (int kh = 0; kh < 3; kh++) {
                    int y = h + kh - 1;
#pragma unroll
                    for (int kw = 0; kw < 3; kw++) {
                        int x = w + kw - 1;
                        if ((unsigned)y < (unsigned)Hh && (unsigned)x < (unsigned)Ww)
                            acc = fmaf(wr[kh * 3 + kw], (float)xc[y * Ww + x], acc);
                    }
                }
            }
        }
        t[j] = acc;
    }

    float g_[8], g2_[8];
#pragma unroll
    for (int j = 0; j < 8; j++) g_[j] = t[j] * __shfl_xor(t[j], 32);
#pragma unroll
    for (int j = 0; j < 8; j++) g2_[j] = __shfl_xor(g_[j], 16);
    float glo[8], ghi[8];
    bool hiq = (q & 1);
#pragma unroll
    for (int j = 0; j < 8; j++) {
        glo[j] = hiq ? g2_[j] : g_[j];
        ghi[j] = hiq ? g_[j] : g2_[j];
    }

    f16* ad = att + (size_t)b * NSET * HW + hw;
#pragma unroll
    for (int j = 0; j < 8; j++) {
        int s = q * 8 + j;
        float acc = Wf[1120 + s];
        const float* wr = &Wf[608 + s * 16];
#pragma unroll
        for (int c = 0; c < 8; c++) acc = fmaf(wr[c], glo[c], acc);
#pragma unroll
        for (int c = 0; c < 8; c++) acc = fmaf(wr[8 + c], ghi[c], acc);
        ad[(size_t)s * HW] = (f16)(acc * Wf[1152 + s]);
    }
}

// K6-v2: 5x5 grouped conv with LDS-staged source rows (NOTE-12).
// Block = 192 thr x 1 group x 1 batch x 4-row strip (grid 16*2*40=1280,
// 3840 waves). Stage rows hA-2..hA+5 x 4cl x 160col as coalesced u32 into
// LDS (row-halo zeroed, col-halo zeroed) -> compute taps via ds_read_u16
// with no bounds checks. 160 of 192 threads compute (1 col, 4px, 4o).
__global__ __launch_bounds__(192) void k6_uf(
        const f16* __restrict__ u1, const float* __restrict__ w,
        const float* __restrict__ bias, f16* __restrict__ uf) {
    __shared__ unsigned UBa[4 * 8 * 82];   // [cl][row][82 u32] f16 stride 164
    __shared__ float wsm[404];
    f16* UB = (f16*)UBa;
    int blk = blockIdx.x;              // 0..1279
    int g   = blk / 80;                // 0..15 uniform
    int rest = blk % 80;
    int b   = rest / 40;
    int hA  = (rest % 40) * 4;
    int tid = threadIdx.x;

    for (int e = tid; e < 400; e += 192) {
        int o = e / 100, r2 = e - o * 100, cl = r2 / 25, tp = r2 - cl * 25;
        wsm[e] = w[(((g * 4 + o) * 4) + cl) * 25 + tp];
    }
    if (tid < 4) wsm[400 + tid] = bias[g * 4 + tid];

    {
        const unsigned* u132 = (const unsigned*)u1;
        for (int e = tid; e < 4 * 8 * 80; e += 192) {
            int cl = e / 640, r = (e / 80) & 7, xw = e % 80;
            int y = hA - 2 + r;
            unsigned v = 0u;
            if ((unsigned)y < (unsigned)Hh)
                v = u132[((size_t)(b * C + g * 4 + cl) * HW >> 1) + y * 80 + xw];
            UBa[cl * 656 + r * 82 + 1 + xw] = v;
        }
        if (tid < 64) {
            int cl = tid >> 4, r = (tid >> 1) & 7, side = tid & 1;
            UBa[cl * 656 + r * 82 + side * 81] = 0u;
        }
    }
    __syncthreads();

    if (tid >= 160) return;
    int w_ = tid;
    int hw0 = hA * Ww + w_;

    float acc[16];                     // [px][o]
#pragma unroll
    for (int i = 0; i < 16; i++) acc[i] = wsm[400 + (i & 3)];

#pragma unroll 1
    for (int cl = 0; cl < 4; cl++) {
        const f16* src = UB + cl * 1312;   // row stride 164, data col x at 2+x
        float tv[40];
#pragma unroll
        for (int r = 0; r < 8; r++)
#pragma unroll
            for (int kw = 0; kw < 5; kw++)
                tv[r * 5 + kw] = (float)src[r * 164 + w_ + kw];
#pragma unroll
        for (int o = 0; o < 4; o++) {
            const float* wr = &wsm[(o * 4 + cl) * 25];
#pragma unroll
            for (int kh = 0; kh < 5; kh++)
#pragma unroll
                for (int kw = 0; kw < 5; kw++) {
                    float wv = wr[kh * 5 + kw];
                    acc[0 * 4 + o] = fmaf(wv, tv[(kh + 0) * 5 + kw], acc[0 * 4 + o]);
                    acc[1 * 4 + o] = fmaf(wv, tv[(kh + 1) * 5 + kw], acc[1 * 4 + o]);
                    acc[2 * 4 + o] = fmaf(wv, tv[(kh + 2) * 5 + kw], acc[2 * 4 + o]);
                    acc[3 * 4 + o] = fmaf(wv, tv[(kh + 3) * 5 + kw], acc[3 * 4 + o]);
                }
        }
    }
    f16* dst = uf + (size_t)(b * C + g * 4) * HW;
#pragma unroll
    for (int o = 0; o < 4; o++)
#pragma unroll
        for (int px = 0; px < 4; px++)
            dst[o * HW + hw0 + px * Ww] = (f16)acc[px * 4 + o];
}

// K7-MFMA-v3: KBA GEMM + LDS staging, f16 I/O, ATT stride 340 (NOTE-13).
constexpr int ATTS = 340;                // f16 units; 170 u32
__global__ __launch_bounds__(256) void k7_mfma2(
        const f16* __restrict__ att, const f16* __restrict__ uf,
        const f16* __restrict__ wp, const float* __restrict__ ga1,
        const float* __restrict__ sca, f16* __restrict__ xmid) {
    __shared__ unsigned UFa[4 * 4 * 82];   // [cl][r][82 u32] = f16 stride 164
    __shared__ unsigned ATTa[32 * 170];    // [s][170 u32]    = f16 stride 340
    f16* UF  = (f16*)UFa;
    f16* ATT = (f16*)ATTa;
    int bi  = blockIdx.x;                // 0..2559
    int g   = bi / 160;                  // uniform
    int rp  = bi % 160;
    int b   = rp / 80;
    int h0  = (rp % 80) * 2;
    int hw0 = h0 * Ww;
    int tid = threadIdx.x;
    int wv  = tid >> 6, lane = tid & 63;
    int m   = lane & 15, q = lane >> 4;

    {
        const unsigned* uf32 = (const unsigned*)uf;
        for (int e = tid; e < 1280; e += 256) {
            int cl = e / 320, r = (e / 80) & 3, xw = e % 80;
            int y = h0 - 1 + r;
            unsigned v = 0u;
            if ((unsigned)y < (unsigned)Hh)
                v = uf32[((size_t)(b * C + g * 4 + cl) * HW >> 1) + y * 80 + xw];
            UFa[cl * 328 + r * 82 + 1 + xw] = v;
        }
        if (tid < 32) {
            int cl = tid >> 3, r = (tid >> 1) & 3, side = tid & 1;
            UFa[cl * 328 + r * 82 + side * 81] = 0u;
        }
    }
    {
        const unsigned* ab32 =
            (const unsigned*)(att + (size_t)b * NSET * HW + hw0);
        for (int e = tid; e < 5120; e += 256) {
            int s = e / 160, pw = e % 160;
            ATTa[s * 170 + pw] = ab32[(size_t)s * (HW >> 1) + pw];
        }
    }

    f16x8 A[8][2];
    const f16* wpg = wp + (size_t)g * 8 * 2 * 64 * 8;
#pragma unroll
    for (int mt = 0; mt < 8; mt++)
#pragma unroll
        for (int c = 0; c < 2; c++)
            A[mt][c] = *(const f16x8*)(wpg + ((mt * 2 + c) * 64 + lane) * 8);

    int off0[8];
#pragma unroll
    for (int j = 0; j < 8; j++) {
        int i = q * 8 + j;
        int cl = i / 9, rr = i - cl * 9, kh = rr / 3, kw = rr - kh * 3;
        off0[j] = cl * 656 + kh * 164 + kw;
    }
    int off1[4];
#pragma unroll
    for (int j = 0; j < 4; j++) {
        int i = 32 + j;                  // cl=3
        int rr = i - 27, kh = rr / 3, kw = rr - kh * 3;
        off1[j] = 3 * 656 + kh * 164 + kw;
    }

    float gav[4], scb[4];
#pragma unroll
    for (int r = 0; r < 4; r++) {
        gav[r] = ga1[g * 4 + r];
        scb[r] = sca[b * 64 + g * 4 + r];
    }

    __syncthreads();
    const f32x4 zero = {0.f, 0.f, 0.f, 0.f};

#pragma unroll 1
    for (int t = wv; t < 20; t += 4) {       // 5 tiles per wave
        int tr = t / 10, col0 = (t - tr * 10) * 16;
        int tbase = tr * 164 + col0 + m + 1;
        int pxb   = tr * 160 + col0 + m;

        f16x8 B0, B1;
#pragma unroll
        for (int j = 0; j < 8; j++) B0[j] = UF[off0[j] + tbase];
        if (q == 0) {
#pragma unroll
            for (int j = 0; j < 4; j++) B1[j] = UF[off1[j] + tbase];
            B1[4] = (f16)1.f;
            B1[5] = (f16)0.f; B1[6] = (f16)0.f; B1[7] = (f16)0.f;
        } else {
#pragma unroll
            for (int j = 0; j < 8; j++) B1[j] = (f16)0.f;
        }

        f32x4 acc[8];
#pragma unroll
        for (int mt = 0; mt < 8; mt++) {
            acc[mt] = __builtin_amdgcn_mfma_f32_16x16x32_f16(A[mt][0], B0, zero, 0, 0, 0);
            acc[mt] = __builtin_amdgcn_mfma_f32_16x16x32_f16(A[mt][1], B1, acc[mt], 0, 0, 0);
        }

        float o4[4] = {0.f, 0.f, 0.f, 0.f};
#pragma unroll
        for (int mt = 0; mt < 8; mt++) {
            float av = (float)ATT[(mt * 4 + q) * ATTS + pxb];
#pragma unroll
            for (int r = 0; r < 4; r++) o4[r] = fmaf(av, acc[mt][r], o4[r]);
        }
#pragma unroll
        for (int r = 0; r < 4; r++) {
            o4[r] += __shfl_xor(o4[r], 16);
            o4[r] += __shfl_xor(o4[r], 32);
        }
        if (q == 0) {
            int hw = hw0 + pxb;
#pragma unroll
            for (int r = 0; r < 4; r++) {
                int co = g * 4 + r;
                float cf = (float)uf[(size_t)(b * C + co) * HW + hw];
                xmid[(size_t)(b * C + co) * HW + hw] =
                    (f16)((o4[r] * gav[r] + cf) * scb[r]);
            }
        }
    }
}

// K89-MFMA-v3: conv3+residual+LN2+FFN; xmid read as f16 B-frags directly.
__global__ __launch_bounds__(64) void k89_mfma(
        const f16* __restrict__ xmid, const float* __restrict__ inp,
        const f16* __restrict__ wk, const float* __restrict__ cbuf,
        float* __restrict__ out) {
    __shared__ float CONST[256];
    __shared__ f16 TBUF[16 * 72];  // [n][k], stride 72

    int tid = threadIdx.x;         // 0..63
    int m = tid & 15, q = tid >> 4;

    CONST[tid] = cbuf[tid];
    CONST[64 + tid] = cbuf[64 + tid];
    CONST[128 + tid] = cbuf[128 + tid];
    CONST[192 + tid] = cbuf[192 + tid];

    f16x8 A3[4][2], A4[8][2], A5[4][2];
#pragma unroll
    for (int mt = 0; mt < 4; mt++)
#pragma unroll
        for (int c = 0; c < 2; c++) {
            A3[mt][c] = *(const f16x8*)(wk + ((8 + mt * 2 + c) * 64 + tid) * 8);
            A5[mt][c] = *(const f16x8*)(wk + ((32 + mt * 2 + c) * 64 + tid) * 8);
        }
#pragma unroll
    for (int mt = 0; mt < 8; mt++)
#pragma unroll
        for (int c = 0; c < 2; c++)
            A4[mt][c] = *(const f16x8*)(wk + ((16 + mt * 2 + c) * 64 + tid) * 8);
    __syncthreads();

    float c3i[16], b5g[16];
#pragma unroll
    for (int mt = 0; mt < 4; mt++)
#pragma unroll
        for (int r = 0; r < 4; r++) {
            c3i[mt * 4 + r] = CONST[mt * 16 + q * 4 + r];
            b5g[mt * 4 + r] = CONST[192 + mt * 16 + q * 4 + r];
        }

    const f32x4 zero = {0.f, 0.f, 0.f, 0.f};

    int tile = blockIdx.x;
    {
        int px0 = tile * 16;
        int b = px0 / HW;
        int hw0 = px0 - b * HW;
        const f16* xb = xmid + (size_t)b * C * HW + hw0 + m;
        const float* ib = inp + (size_t)b * C * HW + hw0 + m;
        float* ob = out + (size_t)b * C * HW + hw0 + m;

        f16x8 BX[2];
#pragma unroll
        for (int c = 0; c < 2; c++)
#pragma unroll
            for (int j = 0; j < 8; j++)
                BX[c][j] = xb[(size_t)(c * 32 + q * 8 + j) * HW];

        f32x4 accY[4];
#pragma unroll
        for (int mt = 0; mt < 4; mt++) {
            accY[mt] = __builtin_amdgcn_mfma_f32_16x16x32_f16(A3[mt][0], BX[0], zero, 0, 0, 0);
            accY[mt] = __builtin_amdgcn_mfma_f32_16x16x32_f16(A3[mt][1], BX[1], accY[mt], 0, 0, 0);
        }
        float y[16];
#pragma unroll
        for (int mt = 0; mt < 4; mt++)
#pragma unroll
            for (int r = 0; r < 4; r++) {
                int co = mt * 16 + q * 4 + r;
                y[mt * 4 + r] = ib[(size_t)co * HW] + accY[mt][r] + c3i[mt * 4 + r];
            }

        float s = 0.f, s2 = 0.f;
#pragma unroll
        for (int i = 0; i < 16; i++) { s += y[i]; s2 += y[i] * y[i]; }
        s  += __shfl_xor(s, 16);  s  += __shfl_xor(s, 32);
        s2 += __shfl_xor(s2, 16); s2 += __shfl_xor(s2, 32);
        float mu  = s * (1.f / 64.f);
        float var = fmaxf(s2 * (1.f / 64.f) - mu * mu, 0.f);
        float rr  = rsqrtf(var + 1e-6f);

#pragma unroll
        for (int mt = 0; mt < 4; mt++)
#pragma unroll
            for (int r = 0; r < 4; r++)
                TBUF[m * 72 + mt * 16 + q * 4 + r] = (f16)(y[mt * 4 + r] - mu);
        __syncthreads();
        f16x8 BV[2];
#pragma unroll
        for (int c = 0; c < 2; c++)
#pragma unroll
            for (int j = 0; j < 8; j++)
                BV[c][j] = TBUF[m * 72 + c * 32 + q * 8 + j];

        f32x4 accT[8];
#pragma unroll
        for (int mt = 0; mt < 8; mt++) {
            accT[mt] = __builtin_amdgcn_mfma_f32_16x16x32_f16(A4[mt][0], BV[0], zero, 0, 0, 0);
            accT[mt] = __builtin_amdgcn_mfma_f32_16x16x32_f16(A4[mt][1], BV[1], accT[mt], 0, 0, 0);
        }
        __syncthreads();

#pragma unroll
        for (int mt = 0; mt < 4; mt++)
#pragma unroll
            for (int r = 0; r < 4; r++) {
                int j = mt * 16 + q * 4 + r;
                float t1 = rr * accT[mt][r] + CONST[64 + j];
                float t2 = rr * accT[mt + 4][r] + CONST[128 + j];
                TBUF[m * 72 + j] = (f16)(t1 * t2);
            }
        __syncthreads();
        f16x8 BG[2];
#pragma unroll
        for (int c = 0; c < 2; c++)
#pragma unroll
            for (int j = 0; j < 8; j++)
                BG[c][j] = TBUF[m * 72 + c * 32 + q * 8 + j];

        f32x4 accO[4];
#pragma unroll
        for (int mt = 0; mt < 4; mt++) {
            accO[mt] = __builtin_amdgcn_mfma_f32_16x16x32_f16(A5[mt][0], BG[0], zero, 0, 0, 0);
            accO[mt] = __builtin_amdgcn_mfma_f32_16x16x32_f16(A5[mt][1], BG[1], accO[mt], 0, 0, 0);
        }
#pragma unroll
        for (int mt = 0; mt < 4; mt++)
#pragma unroll
            for (int r = 0; r < 4; r++) {
                int co = mt * 16 + q * 4 + r;
                ob[(size_t)co * HW] = y[mt * 4 + r] + accO[mt][r] + b5g[mt * 4 + r];
            }
    }
}

extern "C" void kernel_launch(void* const* d_in, const int* in_sizes, int n_in,
                              void* d_out, int out_size, void* d_ws, size_t ws_size,
                              hipStream_t stream) {
    (void)in_sizes; (void)n_in; (void)out_size; (void)ws_size;

    const float* inp     = (const float*)d_in[0];
    const float* ln1_w   = (const float*)d_in[1];
    const float* ln1_b   = (const float*)d_in[2];
    const float* ln2_w   = (const float*)d_in[3];
    const float* ln2_b   = (const float*)d_in[4];
    const float* sca_w   = (const float*)d_in[5];
    const float* sca_b   = (const float*)d_in[6];
    const float* c11a_w  = (const float*)d_in[7];
    const float* c11a_b  = (const float*)d_in[8];
    const float* c11b_w  = (const float*)d_in[9];
    const float* c11b_b  = (const float*)d_in[10];
    const float* c2a_w   = (const float*)d_in[11];
    const float* c2a_b   = (const float*)d_in[12];
    const float* c2b_w   = (const float*)d_in[13];
    const float* c2b_b   = (const float*)d_in[14];
    const float* conv3_w = (const float*)d_in[15];
    const float* conv3_b = (const float*)d_in[16];
    const float* conv4_w = (const float*)d_in[17];
    const float* conv4_b = (const float*)d_in[18];
    const float* conv5_w = (const float*)d_in[19];
    const float* conv5_b = (const float*)d_in[20];
    const float* kb_w    = (const float*)d_in[21];
    const float* kb_b    = (const float*)d_in[22];
    const float* ga1     = (const float*)d_in[23];
    const float* attg    = (const float*)d_in[24];
    const float* beta    = (const float*)d_in[25];
    const float* gamma   = (const float*)d_in[26];

    // ---- ws arena ----
    char* ws = (char*)d_ws;
    size_t off = 0;
    auto alloc = [&](size_t bytes) {
        void* r = ws + off;
        off += (bytes + 255) & ~(size_t)255;
        return r;
    };
    f16*   wpk   = (f16*)alloc(131072 * 2);             // 256 KB packed KBA W
    f16*   wk2   = (f16*)alloc(20480 * 2);              // 40 KB packed A-frags
    float* cbuf  = (float*)alloc(256 * 4);
    float* meanb = (float*)alloc(128 * 4);
    float* scab  = (float*)alloc(128 * 4);
    f16*   x1    = (f16*)alloc((size_t)P * 64 * 2);     // 6.55 MB
    f16*   attb  = (f16*)alloc((size_t)P * 32 * 2);     // 3.28 MB
    f16*   u1    = (f16*)alloc((size_t)P * 64 * 2);     // 6.55 MB
    f16*   ufb   = x1;   // x1 dead after K4
    f16*   xmid  = u1;   // u1 dead after K6

    hipMemsetAsync(meanb, 0, 128 * 4, stream);

    k0_prep  <<<512, 256, 0, stream>>>(kb_w, kb_b, wpk);
    k0c_pack <<<80, 256, 0, stream>>>(c11a_w, conv3_w, beta, conv4_w, ln2_w,
                                      conv5_w, gamma, wk2);
    k0d_const<<<1, 256, 0, stream>>>(conv3_b, beta, conv4_w, ln2_b, conv4_b,
                                     conv5_b, gamma, cbuf);
    k15_ln1u1<<<3200, 64, 0, stream>>>(inp, ln1_w, ln1_b, wk2, c11a_b,
                                       x1, u1);
    k2_mean  <<<512, 256, 0, stream>>>(x1, meanb);
    k3_sca   <<<1, 128, 0, stream>>>(sca_w, sca_b, meanb, scab);
    k4_att2  <<<P / 32, 128, 0, stream>>>(x1, c2a_w, c2a_b, c2b_w, c2b_b,
                                          attg, attb);
    k6_uf    <<<1280, 192, 0, stream>>>(u1, c11b_w, c11b_b, ufb);
    k7_mfma2 <<<2560, 256, 0, stream>>>(attb, ufb, wpk, ga1, scab, xmid);
    k89_mfma <<<3200, 64, 0, stream>>>(xmid, inp, wk2, cbuf, (float*)d_out);
}

// Round 21
// 240.254 us; speedup vs baseline: 1.1566x; 1.0719x over previous
//
#include <hip/hip_runtime.h>
#include <hip/hip_fp16.h>

#define DEVFN __device__ __forceinline__

constexpr int C   = 64;
constexpr int Hh  = 160, Ww = 160, HW = Hh * Ww;   // 25600
constexpr int B   = 2;
constexpr int P   = B * HW;                        // 51200
constexpr int NSET = 32;

typedef _Float16 f16;
typedef f16   f16x8 __attribute__((ext_vector_type(8)));
typedef float f32x4 __attribute__((ext_vector_type(4)));

// NOTE: __launch_bounds__ on every kernel (round 4).
// NOTE-2 (round 5): register arrays statically indexed everywhere.
// NOTE-3 (round 6): >~48 uniform floats/iter don't stream through SGPRs.
// NOTE-4 (round 7): >=4 independent FMA chains per loop body.
// NOTE-5 (round 8): LDS broadcast ~12cyc/b128 on the per-CU LDS pipe.
// NOTE-6 (round 9): enough waves; shrink per-thread state via f16.
// NOTE-7 (round 10): f16 K-packing halves LDS bytes + inst count.
// NOTE-8 (round 11): LDS-bound loops scale with px-per-weight-read.
// NOTE-9 (rounds 12/16/17): >=3 waves/SIMD; hoist packing to prep kernels.
// NOTE-10 (round 13): MFMA A-frags in registers; 16x16x32_f16 layouts; LN
// via shfl_xor(16,32) in B-layout.
// NOTE-11 (round 14): KBA = GEMM + lane-local a-contraction + shfl_xor.
// NOTE-12 (rounds 14/19/20): activations feeding tap/scatter reads must be
// LDS-staged via coalesced u32 loads; per-thread scalar f16 global taps are
// latency-death (k6 r19 58us; k4 had the same defect since r18's f16 x1).
// NOTE-13 (round 18): LDS stride bank math: make (4*stride_dw mod 32)!=0.
// f16 intermediates halve traffic; all paths damped ~0.01.

// K0all: all weight prep in ONE launch.
// e < 131072: KBA pack; e < 151552: A-frag pack; else: bias consts.
__global__ __launch_bounds__(256) void k0all(
        const float* __restrict__ kbw, const float* __restrict__ kbb,
        const float* __restrict__ c11aw, const float* __restrict__ conv3w,
        const float* __restrict__ beta, const float* __restrict__ w4,
        const float* __restrict__ lnw, const float* __restrict__ lnb,
        const float* __restrict__ b4, const float* __restrict__ w5,
        const float* __restrict__ b5, const float* __restrict__ gamma,
        const float* __restrict__ conv3b,
        f16* __restrict__ wp, f16* __restrict__ wk,
        float* __restrict__ cbuf) {
    int e = blockIdx.x * 256 + threadIdx.x;
    if (e < 131072) {
        int j = e & 7, lane = (e >> 3) & 63, c = (e >> 9) & 1,
            mt = (e >> 10) & 7, g = e >> 13;
        int m = lane & 15, q = lane >> 4;
        int row = mt * 16 + m, s = row >> 2, o = row & 3;
        int k = c * 32 + q * 8 + j;
        float v = 0.f;
        if (k < 36)       v = kbw[(size_t)s * 2304 + g * 144 + o * 36 + k];
        else if (k == 36) v = kbb[s * 64 + g * 4 + o];
        wp[e] = (f16)v;
    } else if (e < 151552) {
        int e2 = e - 131072;
        int j = e2 & 7, lane = (e2 >> 3) & 63, seg = e2 >> 9;
        int m = lane & 15, q = lane >> 4;
        float v;
        if (seg < 8) {
            int mt = seg >> 1, c = seg & 1, k = c * 32 + q * 8 + j;
            v = c11aw[(mt * 16 + m) * 64 + k];
        } else if (seg < 16) {
            int s3 = seg - 8, mt = s3 >> 1, c = s3 & 1, k = c * 32 + q * 8 + j;
            int co = mt * 16 + m;
            v = conv3w[co * 64 + k] * beta[co];
        } else if (seg < 32) {
            int s3 = seg - 16, mt = s3 >> 1, c = s3 & 1, k = c * 32 + q * 8 + j;
            v = w4[(mt * 16 + m) * 64 + k] * lnw[k];
        } else {
            int s3 = seg - 32, mt = s3 >> 1, c = s3 & 1, k = c * 32 + q * 8 + j;
            int co = mt * 16 + m;
            v = w5[co * 64 + k] * gamma[co];
        }
        wk[e2] = (f16)v;
    } else if (e < 151808) {
        int t = e - 151552;
        if (t < 64) {
            cbuf[t] = conv3b[t] * beta[t];
        } else if (t < 192) {
            int j = t - 64;
            float a = 0.f;
#pragma unroll 1
            for (int ci = 0; ci < 64; ci++)
                a = fmaf(w4[j * 64 + ci], lnb[ci], a);
            cbuf[t] = a + b4[j];
        } else {
            int co = t - 192;
            cbuf[t] = b5[co] * gamma[co];
        }
    }
}

// K15: fused LN1 + u1 via MFMA; f16 outputs; grid 3200.
__global__ __launch_bounds__(64) void k15_ln1u1(
        const float* __restrict__ inp, const float* __restrict__ lnw,
        const float* __restrict__ lnb, const f16* __restrict__ wk,
        const float* __restrict__ c11ab, f16* __restrict__ x1,
        f16* __restrict__ u1) {
    int tid = threadIdx.x;             // 0..63
    int m = tid & 15, q = tid >> 4;

    f16x8 A[4][2];
#pragma unroll
    for (int mt = 0; mt < 4; mt++)
#pragma unroll
        for (int c = 0; c < 2; c++)
            A[mt][c] = *(const f16x8*)(wk + ((mt * 2 + c) * 64 + tid) * 8);

    float lnwv[16], lnbv[16];
#pragma unroll
    for (int c = 0; c < 2; c++)
#pragma unroll
        for (int j = 0; j < 8; j++) {
            int k = c * 32 + q * 8 + j;
            lnwv[c * 8 + j] = lnw[k];
            lnbv[c * 8 + j] = lnb[k];
        }
    float bco[16];
#pragma unroll
    for (int mt = 0; mt < 4; mt++)
#pragma unroll
        for (int r = 0; r < 4; r++)
            bco[mt * 4 + r] = c11ab[mt * 16 + q * 4 + r];

    const f32x4 zero = {0.f, 0.f, 0.f, 0.f};

    int tile = blockIdx.x;
    {
        int px0 = tile * 16;
        int b = px0 / HW;
        int hw0 = px0 - b * HW;
        const float* ib = inp + (size_t)b * C * HW + hw0 + m;

        float vin[16];
#pragma unroll
        for (int c = 0; c < 2; c++)
#pragma unroll
            for (int j = 0; j < 8; j++)
                vin[c * 8 + j] = ib[(size_t)(c * 32 + q * 8 + j) * HW];

        float s = 0.f, s2 = 0.f;
#pragma unroll
        for (int i = 0; i < 16; i++) { s += vin[i]; s2 += vin[i] * vin[i]; }
        s  += __shfl_xor(s, 16);  s  += __shfl_xor(s, 32);
        s2 += __shfl_xor(s2, 16); s2 += __shfl_xor(s2, 32);
        float mu  = s * (1.f / 64.f);
        float var = fmaxf(s2 * (1.f / 64.f) - mu * mu, 0.f);
        float r   = rsqrtf(var + 1e-6f);

        f16* xo = x1 + (size_t)b * C * HW + hw0 + m;
        f16x8 BX[2];
#pragma unroll
        for (int c = 0; c < 2; c++)
#pragma unroll
            for (int j = 0; j < 8; j++) {
                float v = (vin[c * 8 + j] - mu) * r * lnwv[c * 8 + j] + lnbv[c * 8 + j];
                BX[c][j] = (f16)v;
                xo[(size_t)(c * 32 + q * 8 + j) * HW] = (f16)v;
            }

        f32x4 acc[4];
#pragma unroll
        for (int mt = 0; mt < 4; mt++) {
            acc[mt] = __builtin_amdgcn_mfma_f32_16x16x32_f16(A[mt][0], BX[0], zero, 0, 0, 0);
            acc[mt] = __builtin_amdgcn_mfma_f32_16x16x32_f16(A[mt][1], BX[1], acc[mt], 0, 0, 0);
        }
        f16* uo = u1 + (size_t)b * C * HW + hw0 + m;
#pragma unroll
        for (int mt = 0; mt < 4; mt++)
#pragma unroll
            for (int r2 = 0; r2 < 4; r2++) {
                int co = mt * 16 + q * 4 + r2;
                uo[(size_t)co * HW] = (f16)(acc[mt][r2] + bco[mt * 4 + r2]);
            }
    }
}

// K2: spatial mean of x1 per (b,c); 512 blocks, atomic partials.
__global__ __launch_bounds__(256) void k2_mean(
        const f16* __restrict__ x1, float* __restrict__ meanb) {
    int blk = blockIdx.x;                        // 0..511
    int bc = blk >> 2, quarter = blk & 3;
    const f16* src = x1 + (size_t)bc * HW + quarter * (HW / 4);
    float s = 0.f;
    for (int i = threadIdx.x; i < HW / 4; i += 256) s += (float)src[i];
#pragma unroll
    for (int o = 32; o > 0; o >>= 1) s += __shfl_down(s, o);
    __shared__ float red[4];
    if ((threadIdx.x & 63) == 0) red[threadIdx.x >> 6] = s;
    __syncthreads();
    if (threadIdx.x == 0)
        atomicAdd(&meanb[bc],
                  (red[0] + red[1] + red[2] + red[3]) * (1.f / HW));
}

// K3: sca = sca_w @ mean + sca_b   [B,64]
__global__ __launch_bounds__(256) void k3_sca(
        const float* __restrict__ scaw, const float* __restrict__ scab_,
        const float* __restrict__ meanb, float* __restrict__ sca) {
    int t = threadIdx.x;
    if (t >= 128) return;
    int b = t >> 6, c = t & 63;
    float acc = scab_[c];
#pragma unroll
    for (int k = 0; k < 64; k++)
        acc = fmaf(scaw[c * 64 + k], meanb[b * 64 + k], acc);
    sca[t] = acc;
}

// K4-v3: att with LDS-staged x1 window (NOTE-12). Block = 1 row x 32 cols
// (grid B*160*5=1600); stage 64ch x 3rows x 36col f16 (u32 stride 19,
// 14.6KB, halo zeroed) coalesced; taps via ds_read_u16, branch-free.
// Lane layout/gate shuffles = validated k4v2 scheme.
__global__ __launch_bounds__(128) void k4_att3(
        const f16* __restrict__ x1, const float* __restrict__ c2aw,
        const float* __restrict__ c2ab, const float* __restrict__ c2bw,
        const float* __restrict__ c2bb, const float* __restrict__ attg,
        f16* __restrict__ att) {
    __shared__ unsigned XSa[64 * 3 * 19];   // [ch][row][19 u32] = 38 f16
    __shared__ float Wf[1184];
    f16* XS = (f16*)XSa;
    int tid = threadIdx.x;
    int blk = blockIdx.x;              // 0..1599
    int b  = blk / 800;
    int rem = blk % 800;
    int h  = rem / 5;
    int cb = rem % 5;                  // col block, w0 = 32*cb

    for (int e = tid; e < 1184; e += 128) {
        float v;
        if (e < 576)       v = c2aw[e];
        else if (e < 608)  v = c2ab[e - 576];
        else if (e < 1120) v = c2bw[e - 608];
        else if (e < 1152) v = c2bb[e - 1120];
        else               v = attg[e - 1152];
        Wf[e] = v;
    }
    {
        const unsigned* x32 = (const unsigned*)x1;
        for (int e = tid; e < 64 * 3 * 18; e += 128) {
            int ch = e / 54, r2 = e - ch * 54, row = r2 / 18, cu = r2 - row * 18;
            int y = h - 1 + row;
            int xu = cb * 16 - 1 + cu;           // u32 col index 0..79 valid
            unsigned v = 0u;
            if ((unsigned)y < (unsigned)Hh && (unsigned)xu < 80u)
                v = x32[((size_t)(b * C + ch) * HW >> 1) + y * 80 + xu];
            XSa[ch * 57 + row * 19 + cu] = v;
        }
    }
    __syncthreads();

    int wv = tid >> 6, lane = tid & 63;
    int i = lane & 15, q = lane >> 4;
    int px = wv * 16 + i;              // 0..31 within block
    int w = cb * 32 + px;
    int hw = h * Ww + w;

    // t[j]: o = q*8+j ; taps from LDS: XS[ch*114 + kh*38 + px + kw + 1]
    float t[8];
#pragma unroll
    for (int j = 0; j < 8; j++) {
        int o = q * 8 + j;
        float acc = Wf[576 + o];
#pragma unroll
        for (int k = 0; k < 2; k++) {
            const f16* xc = XS + (2 * o + k) * 114 + px + 1;
            const float* wr = &Wf[(o * 2 + k) * 9];
#pragma unroll
            for (int kh = 0; kh < 3; kh++)
#pragma unroll
                for (int kw = 0; kw < 3; kw++)
                    acc = fmaf(wr[kh * 3 + kw], (float)xc[kh * 38 + kw], acc);
        }
        t[j] = acc;
    }

    float g_[8], g2_[8];
#pragma unroll
    for (int j = 0; j < 8; j++) g_[j] = t[j] * __shfl_xor(t[j], 32);
#pragma unroll
    for (int j = 0; j < 8; j++) g2_[j] = __shfl_xor(g_[j], 16);
    float glo[8], ghi[8];
    bool hiq = (q & 1);
#pragma unroll
    for (int j = 0; j < 8; j++) {
        glo[j] = hiq ? g2_[j] : g_[j];
        ghi[j] = hiq ? g_[j] : g2_[j];
    }

    f16* ad = att + (size_t)b * NSET * HW + hw;
#pragma unroll
    for (int j = 0; j < 8; j++) {
        int s = q * 8 + j;
        float acc = Wf[1120 + s];
        const float* wr = &Wf[608 + s * 16];
#pragma unroll
        for (int c = 0; c < 8; c++) acc = fmaf(wr[c], glo[c], acc);
#pragma unroll
        for (int c = 0; c < 8; c++) acc = fmaf(wr[8 + c], ghi[c], acc);
        ad[(size_t)s * HW] = (f16)(acc * Wf[1152 + s]);
    }
}

// K6-v2: 5x5 grouped conv with LDS-staged source rows (round 20).
__global__ __launch_bounds__(192) void k6_uf(
        const f16* __restrict__ u1, const float* __restrict__ w,
        const float* __restrict__ bias, f16* __restrict__ uf) {
    __shared__ unsigned UBa[4 * 8 * 82];   // [cl][row][82 u32] f16 stride 164
    __shared__ float wsm[404];
    f16* UB = (f16*)UBa;
    int blk = blockIdx.x;              // 0..1279
    int g   = blk / 80;                // 0..15 uniform
    int rest = blk % 80;
    int b   = rest / 40;
    int hA  = (rest % 40) * 4;
    int tid = threadIdx.x;

    for (int e = tid; e < 400; e += 192) {
        int o = e / 100, r2 = e - o * 100, cl = r2 / 25, tp = r2 - cl * 25;
        wsm[e] = w[(((g * 4 + o) * 4) + cl) * 25 + tp];
    }
    if (tid < 4) wsm[400 + tid] = bias[g * 4 + tid];

    {
        const unsigned* u132 = (const unsigned*)u1;
        for (int e = tid; e < 4 * 8 * 80; e += 192) {
            int cl = e / 640, r = (e / 80) & 7, xw = e % 80;
            int y = hA - 2 + r;
            unsigned v = 0u;
            if ((unsigned)y < (unsigned)Hh)
                v = u132[((size_t)(b * C + g * 4 + cl) * HW >> 1) + y * 80 + xw];
            UBa[cl * 656 + r * 82 + 1 + xw] = v;
        }
        if (tid < 64) {
            int cl = tid >> 4, r = (tid >> 1) & 7, side = tid & 1;
            UBa[cl * 656 + r * 82 + side * 81] = 0u;
        }
    }
    __syncthreads();

    if (tid >= 160) return;
    int w_ = tid;
    int hw0 = hA * Ww + w_;

    float acc[16];                     // [px][o]
#pragma unroll
    for (int i = 0; i < 16; i++) acc[i] = wsm[400 + (i & 3)];

#pragma unroll 1
    for (int cl = 0; cl < 4; cl++) {
        const f16* src = UB + cl * 1312;   // row stride 164, data col x at 2+x
        float tv[40];
#pragma unroll
        for (int r = 0; r < 8; r++)
#pragma unroll
            for (int kw = 0; kw < 5; kw++)
                tv[r * 5 + kw] = (float)src[r * 164 + w_ + kw];
#pragma unroll
        for (int o = 0; o < 4; o++) {
            const float* wr = &wsm[(o * 4 + cl) * 25];
#pragma unroll
            for (int kh = 0; kh < 5; kh++)
#pragma unroll
                for (int kw = 0; kw < 5; kw++) {
                    float wv = wr[kh * 5 + kw];
                    acc[0 * 4 + o] = fmaf(wv, tv[(kh + 0) * 5 + kw], acc[0 * 4 + o]);
                    acc[1 * 4 + o] = fmaf(wv, tv[(kh + 1) * 5 + kw], acc[1 * 4 + o]);
                    acc[2 * 4 + o] = fmaf(wv, tv[(kh + 2) * 5 + kw], acc[2 * 4 + o]);
                    acc[3 * 4 + o] = fmaf(wv, tv[(kh + 3) * 5 + kw], acc[3 * 4 + o]);
                }
        }
    }
    f16* dst = uf + (size_t)(b * C + g * 4) * HW;
#pragma unroll
    for (int o = 0; o < 4; o++)
#pragma unroll
        for (int px = 0; px < 4; px++)
            dst[o * HW + hw0 + px * Ww] = (f16)acc[px * 4 + o];
}

// K7-MFMA-v3: KBA GEMM + LDS staging, f16 I/O, ATT stride 340 (NOTE-13).
constexpr int ATTS = 340;                // f16 units; 170 u32
__global__ __launch_bounds__(256) void k7_mfma2(
        const f16* __restrict__ att, const f16* __restrict__ uf,
        const f16* __restrict__ wp, const float* __restrict__ ga1,
        const float* __restrict__ sca, f16* __restrict__ xmid) {
    __shared__ unsigned UFa[4 * 4 * 82];   // [cl][r][82 u32] = f16 stride 164
    __shared__ unsigned ATTa[32 * 170];    // [s][170 u32]    = f16 stride 340
    f16* UF  = (f16*)UFa;
    f16* ATT = (f16*)ATTa;
    int bi  = blockIdx.x;                // 0..2559
    int g   = bi / 160;                  // uniform
    int rp  = bi % 160;
    int b   = rp / 80;
    int h0  = (rp % 80) * 2;
    int hw0 = h0 * Ww;
    int tid = threadIdx.x;
    int wv  = tid >> 6, lane = tid & 63;
    int m   = lane & 15, q = lane >> 4;

    {
        const unsigned* uf32 = (const unsigned*)uf;
        for (int e = tid; e < 1280; e += 256) {
            int cl = e / 320, r = (e / 80) & 3, xw = e % 80;
            int y = h0 - 1 + r;
            unsigned v = 0u;
            if ((unsigned)y < (unsigned)Hh)
                v = uf32[((size_t)(b * C + g * 4 + cl) * HW >> 1) + y * 80 + xw];
            UFa[cl * 328 + r * 82 + 1 + xw] = v;
        }
        if (tid < 32) {
            int cl = tid >> 3, r = (tid >> 1) & 3, side = tid & 1;
            UFa[cl * 328 + r * 82 + side * 81] = 0u;
        }
    }
    {
        const unsigned* ab32 =
            (const unsigned*)(att + (size_t)b * NSET * HW + hw0);
        for (int e = tid; e < 5120; e += 256) {
            int s = e / 160, pw = e % 160;
            ATTa[s * 170 + pw] = ab32[(size_t)s * (HW >> 1) + pw];
        }
    }

    f16x8 A[8][2];
    const f16* wpg = wp + (size_t)g * 8 * 2 * 64 * 8;
#pragma unroll
    for (int mt = 0; mt < 8; mt++)
#pragma unroll
        for (int c = 0; c < 2; c++)
            A[mt][c] = *(const f16x8*)(wpg + ((mt * 2 + c) * 64 + lane) * 8);

    int off0[8];
#pragma unroll
    for (int j = 0; j < 8; j++) {
        int i = q * 8 + j;
        int cl = i / 9, rr = i - cl * 9, kh = rr / 3, kw = rr - kh * 3;
        off0[j] = cl * 656 + kh * 164 + kw;
    }
    int off1[4];
#pragma unroll
    for (int j = 0; j < 4; j++) {
        int i = 32 + j;                  // cl=3
        int rr = i - 27, kh = rr / 3, kw = rr - kh * 3;
        off1[j] = 3 * 656 + kh * 164 + kw;
    }

    float gav[4], scb[4];
#pragma unroll
    for (int r = 0; r < 4; r++) {
        gav[r] = ga1[g * 4 + r];
        scb[r] = sca[b * 64 + g * 4 + r];
    }

    __syncthreads();
    const f32x4 zero = {0.f, 0.f, 0.f, 0.f};

#pragma unroll 1
    for (int t = wv; t < 20; t += 4) {       // 5 tiles per wave
        int tr = t / 10, col0 = (t - tr * 10) * 16;
        int tbase = tr * 164 + col0 + m + 1;
        int pxb   = tr * 160 + col0 + m;

        f16x8 B0, B1;
#pragma unroll
        for (int j = 0; j < 8; j++) B0[j] = UF[off0[j] + tbase];
        if (q == 0) {
#pragma unroll
            for (int j = 0; j < 4; j++) B1[j] = UF[off1[j] + tbase];
            B1[4] = (f16)1.f;
            B1[5] = (f16)0.f; B1[6] = (f16)0.f; B1[7] = (f16)0.f;
        } else {
#pragma unroll
            for (int j = 0; j < 8; j++) B1[j] = (f16)0.f;
        }

        f32x4 acc[8];
#pragma unroll
        for (int mt = 0; mt < 8; mt++) {
            acc[mt] = __builtin_amdgcn_mfma_f32_16x16x32_f16(A[mt][0], B0, zero, 0, 0, 0);
            acc[mt] = __builtin_amdgcn_mfma_f32_16x16x32_f16(A[mt][1], B1, acc[mt], 0, 0, 0);
        }

        float o4[4] = {0.f, 0.f, 0.f, 0.f};
#pragma unroll
        for (int mt = 0; mt < 8; mt++) {
            float av = (float)ATT[(mt * 4 + q) * ATTS + pxb];
#pragma unroll
            for (int r = 0; r < 4; r++) o4[r] = fmaf(av, acc[mt][r], o4[r]);
        }
#pragma unroll
        for (int r = 0; r < 4; r++) {
            o4[r] += __shfl_xor(o4[r], 16);
            o4[r] += __shfl_xor(o4[r], 32);
        }
        if (q == 0) {
            int hw = hw0 + pxb;
#pragma unroll
            for (int r = 0; r < 4; r++) {
                int co = g * 4 + r;
                float cf = (float)uf[(size_t)(b * C + co) * HW + hw];
                xmid[(size_t)(b * C + co) * HW + hw] =
                    (f16)((o4[r] * gav[r] + cf) * scb[r]);
            }
        }
    }
}

// K89-MFMA-v3: conv3+residual+LN2+FFN; xmid read as f16 B-frags directly.
__global__ __launch_bounds__(64) void k89_mfma(
        const f16* __restrict__ xmid, const float* __restrict__ inp,
        const f16* __restrict__ wk, const float* __restrict__ cbuf,
        float* __restrict__ out) {
    __shared__ float CONST[256];
    __shared__ f16 TBUF[16 * 72];  // [n][k], stride 72

    int tid = threadIdx.x;         // 0..63
    int m = tid & 15, q = tid >> 4;

    CONST[tid] = cbuf[tid];
    CONST[64 + tid] = cbuf[64 + tid];
    CONST[128 + tid] = cbuf[128 + tid];
    CONST[192 + tid] = cbuf[192 + tid];

    f16x8 A3[4][2], A4[8][2], A5[4][2];
#pragma unroll
    for (int mt = 0; mt < 4; mt++)
#pragma unroll
        for (int c = 0; c < 2; c++) {
            A3[mt][c] = *(const f16x8*)(wk + ((8 + mt * 2 + c) * 64 + tid) * 8);
            A5[mt][c] = *(const f16x8*)(wk + ((32 + mt * 2 + c) * 64 + tid) * 8);
        }
#pragma unroll
    for (int mt = 0; mt < 8; mt++)
#pragma unroll
        for (int c = 0; c < 2; c++)
            A4[mt][c] = *(const f16x8*)(wk + ((16 + mt * 2 + c) * 64 + tid) * 8);
    __syncthreads();

    float c3i[16], b5g[16];
#pragma unroll
    for (int mt = 0; mt < 4; mt++)
#pragma unroll
        for (int r = 0; r < 4; r++) {
            c3i[mt * 4 + r] = CONST[mt * 16 + q * 4 + r];
            b5g[mt * 4 + r] = CONST[192 + mt * 16 + q * 4 + r];
        }

    const f32x4 zero = {0.f, 0.f, 0.f, 0.f};

    int tile = blockIdx.x;
    {
        int px0 = tile * 16;
        int b = px0 / HW;
        int hw0 = px0 - b * HW;
        const f16* xb = xmid + (size_t)b * C * HW + hw0 + m;
        const float* ib = inp + (size_t)b * C * HW + hw0 + m;
        float* ob = out + (size_t)b * C * HW + hw0 + m;

        f16x8 BX[2];
#pragma unroll
        for (int c = 0; c < 2; c++)
#pragma unroll
            for (int j = 0; j < 8; j++)
                BX[c][j] = xb[(size_t)(c * 32 + q * 8 + j) * HW];

        f32x4 accY[4];
#pragma unroll
        for (int mt = 0; mt < 4; mt++) {
            accY[mt] = __builtin_amdgcn_mfma_f32_16x16x32_f16(A3[mt][0], BX[0], zero, 0, 0, 0);
            accY[mt] = __builtin_amdgcn_mfma_f32_16x16x32_f16(A3[mt][1], BX[1], accY[mt], 0, 0, 0);
        }
        float y[16];
#pragma unroll
        for (int mt = 0; mt < 4; mt++)
#pragma unroll
            for (int r = 0; r < 4; r++) {
                int co = mt * 16 + q * 4 + r;
                y[mt * 4 + r] = ib[(size_t)co * HW] + accY[mt][r] + c3i[mt * 4 + r];
            }

        float s = 0.f, s2 = 0.f;
#pragma unroll
        for (int i = 0; i < 16; i++) { s += y[i]; s2 += y[i] * y[i]; }
        s  += __shfl_xor(s, 16);  s  += __shfl_xor(s, 32);
        s2 += __shfl_xor(s2, 16); s2 += __shfl_xor(s2, 32);
        float mu  = s * (1.f / 64.f);
        float var = fmaxf(s2 * (1.f / 64.f) - mu * mu, 0.f);
        float rr  = rsqrtf(var + 1e-6f);

#pragma unroll
        for (int mt = 0; mt < 4; mt++)
#pragma unroll
            for (int r = 0; r < 4; r++)
                TBUF[m * 72 + mt * 16 + q * 4 + r] = (f16)(y[mt * 4 + r] - mu);
        __syncthreads();
        f16x8 BV[2];
#pragma unroll
        for (int c = 0; c < 2; c++)
#pragma unroll
            for (int j = 0; j < 8; j++)
                BV[c][j] = TBUF[m * 72 + c * 32 + q * 8 + j];

        f32x4 accT[8];
#pragma unroll
        for (int mt = 0; mt < 8; mt++) {
            accT[mt] = __builtin_amdgcn_mfma_f32_16x16x32_f16(A4[mt][0], BV[0], zero, 0, 0, 0);
            accT[mt] = __builtin_amdgcn_mfma_f32_16x16x32_f16(A4[mt][1], BV[1], accT[mt], 0, 0, 0);
        }
        __syncthreads();

#pragma unroll
        for (int mt = 0; mt < 4; mt++)
#pragma unroll
            for (int r = 0; r < 4; r++) {
                int j = mt * 16 + q * 4 + r;
                float t1 = rr * accT[mt][r] + CONST[64 + j];
                float t2 = rr * accT[mt + 4][r] + CONST[128 + j];
                TBUF[m * 72 + j] = (f16)(t1 * t2);
            }
        __syncthreads();
        f16x8 BG[2];
#pragma unroll
        for (int c = 0; c < 2; c++)
#pragma unroll
            for (int j = 0; j < 8; j++)
                BG[c][j] = TBUF[m * 72 + c * 32 + q * 8 + j];

        f32x4 accO[4];
#pragma unroll
        for (int mt = 0; mt < 4; mt++) {
            accO[mt] = __builtin_amdgcn_mfma_f32_16x16x32_f16(A5[mt][0], BG[0], zero, 0, 0, 0);
            accO[mt] = __builtin_amdgcn_mfma_f32_16x16x32_f16(A5[mt][1], BG[1], accO[mt], 0, 0, 0);
        }
#pragma unroll
        for (int mt = 0; mt < 4; mt++)
#pragma unroll
            for (int r = 0; r < 4; r++) {
                int co = mt * 16 + q * 4 + r;
                ob[(size_t)co * HW] = y[mt * 4 + r] + accO[mt][r] + b5g[mt * 4 + r];
            }
    }
}

extern "C" void kernel_launch(void* const* d_in, const int* in_sizes, int n_in,
                              void* d_out, int out_size, void* d_ws, size_t ws_size,
                              hipStream_t stream) {
    (void)in_sizes; (void)n_in; (void)out_size; (void)ws_size;

    const float* inp     = (const float*)d_in[0];
    const float* ln1_w   = (const float*)d_in[1];
    const float* ln1_b   = (const float*)d_in[2];
    const float* ln2_w   = (const float*)d_in[3];
    const float* ln2_b   = (const float*)d_in[4];
    const float* sca_w   = (const float*)d_in[5];
    const float* sca_b   = (const float*)d_in[6];
    const float* c11a_w  = (const float*)d_in[7];
    const float* c11a_b  = (const float*)d_in[8];
    const float* c11b_w  = (const float*)d_in[9];
    const float* c11b_b  = (const float*)d_in[10];
    const float* c2a_w   = (const float*)d_in[11];
    const float* c2a_b   = (const float*)d_in[12];
    const float* c2b_w   = (const float*)d_in[13];
    const float* c2b_b   = (const float*)d_in[14];
    const float* conv3_w = (const float*)d_in[15];
    const float* conv3_b = (const float*)d_in[16];
    const float* conv4_w = (const float*)d_in[17];
    const float* conv4_b = (const float*)d_in[18];
    const float* conv5_w = (const float*)d_in[19];
    const float* conv5_b = (const float*)d_in[20];
    const float* kb_w    = (const float*)d_in[21];
    const float* kb_b    = (const float*)d_in[22];
    const float* ga1     = (const float*)d_in[23];
    const float* attg    = (const float*)d_in[24];
    const float* beta    = (const float*)d_in[25];
    const float* gamma   = (const float*)d_in[26];

    // ---- ws arena ----
    char* ws = (char*)d_ws;
    size_t off = 0;
    auto alloc = [&](size_t bytes) {
        void* r = ws + off;
        off += (bytes + 255) & ~(size_t)255;
        return r;
    };
    f16*   wpk   = (f16*)alloc(131072 * 2);             // 256 KB packed KBA W
    f16*   wk2   = (f16*)alloc(20480 * 2);              // 40 KB packed A-frags
    float* cbuf  = (float*)alloc(256 * 4);
    float* meanb = (float*)alloc(128 * 4);
    float* scab  = (float*)alloc(128 * 4);
    f16*   x1    = (f16*)alloc((size_t)P * 64 * 2);     // 6.55 MB
    f16*   attb  = (f16*)alloc((size_t)P * 32 * 2);     // 3.28 MB
    f16*   u1    = (f16*)alloc((size_t)P * 64 * 2);     // 6.55 MB
    f16*   ufb   = x1;   // x1 dead after K4
    f16*   xmid  = u1;   // u1 dead after K6

    hipMemsetAsync(meanb, 0, 128 * 4, stream);

    k0all    <<<593, 256, 0, stream>>>(kb_w, kb_b, c11a_w, conv3_w, beta,
                                       conv4_w, ln2_w, ln2_b, conv4_b,
                                       conv5_w, conv5_b, gamma, conv3_b,
                                       wpk, wk2, cbuf);
    k15_ln1u1<<<3200, 64, 0, stream>>>(inp, ln1_w, ln1_b, wk2, c11a_b,
                                       x1, u1);
    k2_mean  <<<512, 256, 0, stream>>>(x1, meanb);
    k3_sca   <<<1, 128, 0, stream>>>(sca_w, sca_b, meanb, scab);
    k4_att3  <<<1600, 128, 0, stream>>>(x1, c2a_w, c2a_b, c2b_w, c2b_b,
                                        attg, attb);
    k6_uf    <<<1280, 192, 0, stream>>>(u1, c11b_w, c11b_b, ufb);
    k7_mfma2 <<<2560, 256, 0, stream>>>(attb, ufb, wpk, ga1, scab, xmid);
    k89_mfma <<<3200, 64, 0, stream>>>(xmid, inp, wk2, cbuf, (float*)d_out);
}